// Round 24
// baseline (146.446 us; speedup 1.0000x reference)
//
#include <hip/hip_runtime.h>
#include <math.h>

#define BDIM 8
#define NSEQ 4096
#define DDIM 768
#define HDIM 256
#define CH 64

// ---------------- kernel 1: column sums over N (float4, atomics) ----------------
__global__ __launch_bounds__(192)
void colsum_kernel(const float* __restrict__ x, float* __restrict__ csum) {
    int blk = blockIdx.x;          // B*CH
    int ch = blk % CH;
    int b  = blk / CH;
    int t  = threadIdx.x;          // 0..191, one float4 column each
    const int nper = NSEQ / CH;    // 64
    const float4* p = reinterpret_cast<const float4*>(
        x + ((size_t)b * NSEQ + (size_t)ch * nper) * DDIM) + t;
    float4 acc = make_float4(0.f, 0.f, 0.f, 0.f);
    #pragma unroll 8
    for (int i = 0; i < nper; ++i) {
        float4 v = p[(size_t)i * (DDIM / 4)];
        acc.x += v.x; acc.y += v.y; acc.z += v.z; acc.w += v.w;
    }
    float* c = csum + b * DDIM + t * 4;
    atomicAdd(c + 0, acc.x);
    atomicAdd(c + 1, acc.y);
    atomicAdd(c + 2, acc.z);
    atomicAdd(c + 3, acc.w);
}

// ---------------- kernel 1b: dW := b2 (so mlp_dw atomics fold the bias in) ----------------
__global__ __launch_bounds__(256)
void dwinit_kernel(const float* __restrict__ b2, float* __restrict__ dW) {
    int idx = blockIdx.x * 256 + threadIdx.x;   // 0..6143
    dW[idx] = b2[idx % DDIM];
}

// ---------------- kernel 2a: h = gelu(c @ w1 + b1), one block per (b,hh) ----------------
__global__ __launch_bounds__(64)
void mlp_h_kernel(const float* __restrict__ csum, const float* __restrict__ w1,
                  const float* __restrict__ b1, float* __restrict__ h) {
    const int blk = blockIdx.x;
    const int hh = blk & (HDIM - 1);
    const int b  = blk >> 8;
    const int l  = threadIdx.x;
    const float* c = csum + b * DDIM;
    const float* w = w1 + hh;
    float acc = 0.f;
    #pragma unroll
    for (int j = 0; j < 12; ++j) {
        int d = l * 12 + j;
        acc = fmaf(c[d], w[(size_t)d * HDIM], acc);
    }
    #pragma unroll
    for (int off = 32; off; off >>= 1) acc += __shfl_down(acc, off);
    if (l == 0) {
        float a = acc * (1.0f / NSEQ) + b1[hh];
        float x3 = a * a * a;
        float g = 0.5f * a * (1.0f + tanhf(0.7978845608028654f * (a + 0.044715f * x3)));
        h[b * HDIM + hh] = g;
    }
}

// ---------------- kernel 2b: dW += h @ w2 (partial j-chunks, atomics) ----------------
__global__ __launch_bounds__(64)
void mlp_dw_kernel(const float* __restrict__ h, const float* __restrict__ w2,
                   float* __restrict__ dW) {
    const int blk = blockIdx.x;
    const int dc = blk % 12;
    const int jc = (blk / 12) & 3;
    const int b  = blk / 48;
    const int l  = threadIdx.x;
    __shared__ float hs[64];
    hs[l] = h[b * HDIM + jc * 64 + l];
    __syncthreads();
    const int d = dc * 64 + l;
    const float* w = w2 + (size_t)(jc * 64) * DDIM + d;
    float acc = 0.f;
    #pragma unroll 8
    for (int j = 0; j < 64; ++j) acc = fmaf(hs[j], w[(size_t)j * DDIM], acc);
    atomicAdd(&dW[b * DDIM + d], acc);
}

// ======================= register-resident FFT machinery =======================

__device__ __forceinline__ void cmulc(float& r, float& i, float br, float bi) {
    float tr = r * br - i * bi;
    float ti = r * bi + i * br;
    r = tr; i = ti;
}

// xor-shuffle across 64 lanes: DPP for 1,2; ds_swizzle for 4,8,16; bpermute for 32
template<int MASK>
__device__ __forceinline__ float xsh(float v, int l) {
    int iv = __float_as_int(v);
    if constexpr (MASK == 1)       iv = __builtin_amdgcn_mov_dpp(iv, 0xB1, 0xF, 0xF, false);
    else if constexpr (MASK == 2)  iv = __builtin_amdgcn_mov_dpp(iv, 0x4E, 0xF, 0xF, false);
    else if constexpr (MASK == 32) iv = __builtin_amdgcn_ds_bpermute((l ^ 32) << 2, iv);
    else                           iv = __builtin_amdgcn_ds_swizzle(iv, (MASK << 10) | 0x1F);
    return __int_as_float(iv);
}

// Select-free DIF butterfly stage over index space `idx` (distance M), with data
// of index i living at lane sigma(i) such that pairing i^M == lane xor MASK.
// Forward (INV=false): natural-in -> bitrev-out. In permuted space (idx=rk,
// MASK=32/M): bitrev-in -> natural-out. lo: a+b; hi: (a-b)*W_{2M}^{idx&(M-1)}.
template<int M, int MASK, bool INV>
__device__ __forceinline__ void stageP(float* zr, float* zi, int l, int idx) {
    constexpr float SG = INV ? 1.f : -1.f;
    float wc = 1.f, ws = 0.f;
    if constexpr (M > 1) {
        float jj = (float)(idx & (M - 1));
        __sincosf(SG * (3.14159265358979323846f / M) * jj, &ws, &wc);
    }
    const bool hi = (idx & M) != 0;
    const float sgn = hi ? -1.f : 1.f;
    const float wc2 = hi ? wc : 1.f;
    const float ws2 = hi ? ws : 0.f;
    #pragma unroll
    for (int j = 0; j < 12; ++j) {
        float pr = xsh<MASK>(zr[j], l), pi = xsh<MASK>(zi[j], l);
        float tr = fmaf(sgn, zr[j], pr);
        float ti = fmaf(sgn, zi[j], pi);
        zr[j] = wc2 * tr - ws2 * ti;
        zi[j] = wc2 * ti + ws2 * tr;
    }
}

// 12-point DFT over registers (input reg n1, output reg k1; INV conjugates)
template<bool INV>
__device__ __forceinline__ void dft12(float* zr, float* zi) {
    constexpr float C1 = 0.8660254037844386f;
    constexpr float SG = INV ? 1.f : -1.f;
    constexpr float E  = INV ? -C1 : C1;
    float sr[3][4], si[3][4];
    #pragma unroll
    for (int b = 0; b < 3; ++b) {
        float x0r = zr[b],     x0i = zi[b];
        float x1r = zr[3 + b], x1i = zi[3 + b];
        float x2r = zr[6 + b], x2i = zi[6 + b];
        float x3r = zr[9 + b], x3i = zi[9 + b];
        float t0r = x0r + x2r, t0i = x0i + x2i;
        float t1r = x0r - x2r, t1i = x0i - x2i;
        float t2r = x1r + x3r, t2i = x1i + x3i;
        float t3r = x1r - x3r, t3i = x1i - x3i;
        sr[b][0] = t0r + t2r; si[b][0] = t0i + t2i;
        sr[b][2] = t0r - t2r; si[b][2] = t0i - t2i;
        if constexpr (!INV) {
            sr[b][1] = t1r + t3i; si[b][1] = t1i - t3r;
            sr[b][3] = t1r - t3i; si[b][3] = t1i + t3r;
        } else {
            sr[b][1] = t1r - t3i; si[b][1] = t1i + t3r;
            sr[b][3] = t1r + t3i; si[b][3] = t1i - t3r;
        }
    }
    cmulc(sr[1][1], si[1][1], C1,  SG * 0.5f);
    cmulc(sr[1][2], si[1][2], 0.5f, SG * C1);
    { float t = sr[1][3]; sr[1][3] = -SG * si[1][3]; si[1][3] = SG * t; }
    cmulc(sr[2][1], si[2][1], 0.5f,  SG * C1);
    cmulc(sr[2][2], si[2][2], -0.5f, SG * C1);
    sr[2][3] = -sr[2][3]; si[2][3] = -si[2][3];
    #pragma unroll
    for (int p = 0; p < 4; ++p) {
        float x0r = sr[0][p], x0i = si[0][p];
        float x1r = sr[1][p], x1i = si[1][p];
        float x2r = sr[2][p], x2i = si[2][p];
        float tr = x1r + x2r, ti = x1i + x2i;
        float ur = x1r - x2r, ui = x1i - x2i;
        float br = x0r - 0.5f * tr, bi = x0i - 0.5f * ti;
        zr[p]     = x0r + tr;        zi[p]     = x0i + ti;
        zr[4 + p] = br + E * ui;     zi[4 + p] = bi - E * ur;
        zr[8 + p] = br - E * ui;     zi[8 + p] = bi + E * ur;
    }
}

// modReLU effective multiplier, algebraic form:
// w*relu(|w|m+b)/(|w|m) = (|w|m+b > 0) ? w + sign(w)*b*inv_m : 0
__device__ __forceinline__ float geff2(float w, float m, float inv_m, float b) {
    float g = fmaf(__builtin_copysignf(1.0f, w), b * inv_m, w);
    return (fmaf(fabsf(w), m, b) > 0.0f) ? g : 0.0f;
}

// filter math for one spectral slot: Zk=(Zkr,Zki), partner Zn=(Znr,Zni), index kx
__device__ __forceinline__ void filt_core(
    float Zkr, float Zki, float Znr, float Zni, int kx,
    const float* __restrict__ wb1, const float* __restrict__ wb2,
    const float* __restrict__ dwb, const float* __restrict__ bias,
    float& outR, float& outI) {
    const int nk = kx ? (DDIM - kx) : 0;
    float F1r = 0.5f * (Zkr + Znr), F1i = 0.5f * (Zki - Zni);
    float F2r = 0.5f * (Zki + Zni), F2i = 0.5f * (Znr - Zkr);
    float s1 = fmaxf(fmaf(F1r, F1r, F1i * F1i), 1e-24f);
    float s2 = fmaxf(fmaf(F2r, F2r, F2i * F2i), 1e-24f);
    float im1 = rsqrtf(s1), im2 = rsqrtf(s2);
    float m1 = s1 * im1,   m2 = s2 * im2;
    float dk = dwb[kx], dn = dwb[nk];
    float bk = bias[kx], bn = bias[nk];
    float w1k = wb1[kx] + dk, w1n = wb1[nk] + dn;
    float w2k = wb2[kx] + dk, w2n = wb2[nk] + dn;
    float g1 = 0.5f * (geff2(w1k, m1, im1, bk) + geff2(w1n, m1, im1, bn));
    float g2 = 0.5f * (geff2(w2k, m2, im2, bk) + geff2(w2n, m2, im2, bn));
    outR = g1 * F1r - g2 * F2i;
    outI = g1 * F1i + g2 * F2r;
}

// one filter PAIR step, members A=J and B=11-J processed together (slot kx = 64*reg + rk).
// Wave partner of reg A is reg B's OLD value at lane src (and vice versa) -> no snapshot.
// rk==0 (<=> l==0): partner of A is old reg (12-J)%12 at lane 0 -> 2-reg rolling save;
// partner of B is old reg J+1 (future pair, still old), except J=5 (reg-6 self-pair).
template<int J>
__device__ __forceinline__ void filt_pair(
    float* zr, float* zi, float& svR, float& svI,
    int l, int rk, int src,
    const float* __restrict__ wb1, const float* __restrict__ wb2,
    const float* __restrict__ dwb, const float* __restrict__ bias) {
    constexpr int A = J, B = 11 - J;
    const float aZr = zr[A], aZi = zi[A];   // old A
    const float bZr = zr[B], bZi = zi[B];   // old B
    float paR = __int_as_float(__builtin_amdgcn_ds_bpermute(src, __float_as_int(bZr)));
    float paI = __int_as_float(__builtin_amdgcn_ds_bpermute(src, __float_as_int(bZi)));
    float pbR = __int_as_float(__builtin_amdgcn_ds_bpermute(src, __float_as_int(aZr)));
    float pbI = __int_as_float(__builtin_amdgcn_ds_bpermute(src, __float_as_int(aZi)));
    float a0r, a0i;
    if constexpr (J == 0) { a0r = aZr; a0i = aZi; }      // k=0 self-pair
    else                  { a0r = svR; a0i = svI; }      // old reg 12-J from prev pair
    float b0r, b0i;
    if constexpr (J == 5) { b0r = bZr; b0i = bZi; }      // k=384 self-pair (reg 6)
    else                  { b0r = zr[J + 1]; b0i = zi[J + 1]; }  // future pair, still old
    paR = (l == 0) ? a0r : paR;  paI = (l == 0) ? a0i : paI;
    pbR = (l == 0) ? b0r : pbR;  pbI = (l == 0) ? b0i : pbI;
    svR = bZr; svI = bZi;
    filt_core(aZr, aZi, paR, paI, 64 * A + rk, wb1, wb2, dwb, bias, zr[A], zi[A]);
    filt_core(bZr, bZi, pbR, pbI, 64 * B + rk, wb1, wb2, dwb, bias, zr[B], zi[B]);
}

// ---------------- kernel 3: register-resident FFT -> filter -> iFFT ----------------
// n = n1 + 12*n2 (reg n1, lane n2). Both lane-FFT directions are select-free DIF.
// min 5 waves/EU: VGPR budget 102 >= natural need 88 (no squeeze, no spill) while
// declaring higher residency than min4 (the measured residency ~= 0.8 x declared min).
__global__ __launch_bounds__(256, 5)
void fftmix_kernel(const float* __restrict__ x, const float* __restrict__ Wb,
                   const float* __restrict__ dW, const float* __restrict__ bias,
                   float* __restrict__ out) {
    const int l  = threadIdx.x & 63;
    const int wv = threadIdx.x >> 6;
    const int pair = blockIdx.x * 4 + wv;     // [0, 16384)
    const int r1 = pair * 2;
    const int bb = r1 >> 12;
    const int sq = r1 & (NSEQ - 1);
    const int rk = __brev((unsigned)l) >> 26; // bitrev6(l) = k2 this lane holds post-DIF

    // ---- load z = x[r1] + i*x[r1+1]; lane l owns elements [12*l, 12*l+12) ----
    float zr[12], zi[12];
    {
        const float4* p1 = reinterpret_cast<const float4*>(x + (size_t)r1 * DDIM + 12 * l);
        const float4* p2 = reinterpret_cast<const float4*>(x + (size_t)(r1 + 1) * DDIM + 12 * l);
        float4 a0 = p1[0], a1 = p1[1], a2 = p1[2];
        float4 b0 = p2[0], b1_ = p2[1], b2_ = p2[2];
        zr[0] = a0.x; zr[1] = a0.y; zr[2] = a0.z; zr[3] = a0.w;
        zr[4] = a1.x; zr[5] = a1.y; zr[6] = a1.z; zr[7] = a1.w;
        zr[8] = a2.x; zr[9] = a2.y; zr[10] = a2.z; zr[11] = a2.w;
        zi[0] = b0.x; zi[1] = b0.y; zi[2] = b0.z; zi[3] = b0.w;
        zi[4] = b1_.x; zi[5] = b1_.y; zi[6] = b1_.z; zi[7] = b1_.w;
        zi[8] = b2_.x; zi[9] = b2_.y; zi[10] = b2_.z; zi[11] = b2_.w;
    }

    // ---- forward DIF64 across lanes (natural n2 in -> k2 = rk at lane l) ----
    stageP<32, 32, false>(zr, zi, l, l); stageP<16, 16, false>(zr, zi, l, l);
    stageP<8,  8,  false>(zr, zi, l, l); stageP<4,  4,  false>(zr, zi, l, l);
    stageP<2,  2,  false>(zr, zi, l, l); stageP<1,  1,  false>(zr, zi, l, l);

    // ---- middle twiddle: reg j *= W768^{j * rk} ----
    {
        const float th = -(6.283185307179586f / DDIM) * (float)rk;
        #pragma unroll
        for (int j = 1; j < 12; ++j) {
            float s, c;
            __sincosf(th * (float)j, &s, &c);
            cmulc(zr[j], zi[j], c, s);
        }
    }

    // ---- DFT12 over registers: reg k1 = Z[64*k1 + rk] ----
    dft12<false>(zr, zi);

    // ---- filter + modReLU, Hermitian register-pairs (J, 11-J) together ----
    {
        const int prk = (64 - rk) & 63;                          // partner k2
        const int src = ((__brev((unsigned)prk) >> 26)) << 2;    // its lane * 4
        const float* wb1 = Wb + (size_t)sq * DDIM;
        const float* wb2 = wb1 + DDIM;
        const float* dwb = dW + (size_t)bb * DDIM;   // includes b2
        float svR = 0.f, svI = 0.f;                  // rolling lane-0 save
        filt_pair<0>(zr, zi, svR, svI, l, rk, src, wb1, wb2, dwb, bias);
        filt_pair<1>(zr, zi, svR, svI, l, rk, src, wb1, wb2, dwb, bias);
        filt_pair<2>(zr, zi, svR, svI, l, rk, src, wb1, wb2, dwb, bias);
        filt_pair<3>(zr, zi, svR, svI, l, rk, src, wb1, wb2, dwb, bias);
        filt_pair<4>(zr, zi, svR, svI, l, rk, src, wb1, wb2, dwb, bias);
        filt_pair<5>(zr, zi, svR, svI, l, rk, src, wb1, wb2, dwb, bias);
    }

    // ---- inverse: DFT12 over registers (k1 -> n1) ----
    dft12<true>(zr, zi);

    // ---- inverse twiddle: reg j *= W768^{+j * rk} ----
    {
        const float th = (6.283185307179586f / DDIM) * (float)rk;
        #pragma unroll
        for (int j = 1; j < 12; ++j) {
            float s, c;
            __sincosf(th * (float)j, &s, &c);
            cmulc(zr[j], zi[j], c, s);
        }
    }

    // ---- inverse DIF64 in permuted (rk) space: bitrev in -> NATURAL n2 = l out ----
    stageP<32, 1,  true>(zr, zi, l, rk); stageP<16, 2,  true>(zr, zi, l, rk);
    stageP<8,  4,  true>(zr, zi, l, rk); stageP<4,  8,  true>(zr, zi, l, rk);
    stageP<2,  16, true>(zr, zi, l, rk); stageP<1,  32, true>(zr, zi, l, rk);

    // ---- store: lane l holds y[12*l .. 12*l+12); y1 = Re/768, y2 = Im/768 ----
    {
        constexpr float inv = 1.0f / DDIM;
        float4* o1 = reinterpret_cast<float4*>(out + (size_t)r1 * DDIM + 12 * l);
        float4* o2 = reinterpret_cast<float4*>(out + (size_t)(r1 + 1) * DDIM + 12 * l);
        o1[0] = make_float4(zr[0] * inv, zr[1] * inv, zr[2] * inv, zr[3] * inv);
        o1[1] = make_float4(zr[4] * inv, zr[5] * inv, zr[6] * inv, zr[7] * inv);
        o1[2] = make_float4(zr[8] * inv, zr[9] * inv, zr[10] * inv, zr[11] * inv);
        o2[0] = make_float4(zi[0] * inv, zi[1] * inv, zi[2] * inv, zi[3] * inv);
        o2[1] = make_float4(zi[4] * inv, zi[5] * inv, zi[6] * inv, zi[7] * inv);
        o2[2] = make_float4(zi[8] * inv, zi[9] * inv, zi[10] * inv, zi[11] * inv);
    }
}

extern "C" void kernel_launch(void* const* d_in, const int* in_sizes, int n_in,
                              void* d_out, int out_size, void* d_ws, size_t ws_size,
                              hipStream_t stream) {
    const float* x    = (const float*)d_in[0];
    const float* Wb   = (const float*)d_in[1];
    const float* bias = (const float*)d_in[2];
    const float* w1   = (const float*)d_in[3];
    const float* b1   = (const float*)d_in[4];
    const float* w2   = (const float*)d_in[5];
    const float* b2   = (const float*)d_in[6];
    float* out = (float*)d_out;

    float* csum = (float*)d_ws;                 // B*D floats
    float* dW   = csum + BDIM * DDIM;           // B*D floats = b2 + h@w2
    float* h    = dW + BDIM * DDIM;             // B*H floats

    hipMemsetAsync(csum, 0, BDIM * DDIM * sizeof(float), stream);
    dwinit_kernel<<<(BDIM * DDIM) / 256, 256, 0, stream>>>(b2, dW);
    colsum_kernel<<<BDIM * CH, 192, 0, stream>>>(x, csum);
    mlp_h_kernel<<<BDIM * HDIM, 64, 0, stream>>>(csum, w1, b1, h);
    mlp_dw_kernel<<<BDIM * 4 * 12, 64, 0, stream>>>(h, w2, dW);
    fftmix_kernel<<<(BDIM * NSEQ / 2) / 4, 256, 0, stream>>>(x, Wb, dW, bias, out);
}

// Round 25
// 117.378 us; speedup vs baseline: 1.2476x; 1.2476x over previous
//
#include <hip/hip_runtime.h>
#include <math.h>

#define BDIM 8
#define NSEQ 4096
#define DDIM 768
#define HDIM 256
#define CH 64

// ---------------- kernel 1: column sums over N (float4, atomics) ----------------
__global__ __launch_bounds__(192)
void colsum_kernel(const float* __restrict__ x, float* __restrict__ csum) {
    int blk = blockIdx.x;          // B*CH
    int ch = blk % CH;
    int b  = blk / CH;
    int t  = threadIdx.x;          // 0..191, one float4 column each
    const int nper = NSEQ / CH;    // 64
    const float4* p = reinterpret_cast<const float4*>(
        x + ((size_t)b * NSEQ + (size_t)ch * nper) * DDIM) + t;
    float4 acc = make_float4(0.f, 0.f, 0.f, 0.f);
    #pragma unroll 8
    for (int i = 0; i < nper; ++i) {
        float4 v = p[(size_t)i * (DDIM / 4)];
        acc.x += v.x; acc.y += v.y; acc.z += v.z; acc.w += v.w;
    }
    float* c = csum + b * DDIM + t * 4;
    atomicAdd(c + 0, acc.x);
    atomicAdd(c + 1, acc.y);
    atomicAdd(c + 2, acc.z);
    atomicAdd(c + 3, acc.w);
}

// ---------------- kernel 1b: dW := b2 (so mlp_dw atomics fold the bias in) ----------------
__global__ __launch_bounds__(256)
void dwinit_kernel(const float* __restrict__ b2, float* __restrict__ dW) {
    int idx = blockIdx.x * 256 + threadIdx.x;   // 0..6143
    dW[idx] = b2[idx % DDIM];
}

// ---------------- kernel 2a: h = gelu(c @ w1 + b1), one block per (b,hh) ----------------
__global__ __launch_bounds__(64)
void mlp_h_kernel(const float* __restrict__ csum, const float* __restrict__ w1,
                  const float* __restrict__ b1, float* __restrict__ h) {
    const int blk = blockIdx.x;
    const int hh = blk & (HDIM - 1);
    const int b  = blk >> 8;
    const int l  = threadIdx.x;
    const float* c = csum + b * DDIM;
    const float* w = w1 + hh;
    float acc = 0.f;
    #pragma unroll
    for (int j = 0; j < 12; ++j) {
        int d = l * 12 + j;
        acc = fmaf(c[d], w[(size_t)d * HDIM], acc);
    }
    #pragma unroll
    for (int off = 32; off; off >>= 1) acc += __shfl_down(acc, off);
    if (l == 0) {
        float a = acc * (1.0f / NSEQ) + b1[hh];
        float x3 = a * a * a;
        float g = 0.5f * a * (1.0f + tanhf(0.7978845608028654f * (a + 0.044715f * x3)));
        h[b * HDIM + hh] = g;
    }
}

// ---------------- kernel 2b: dW += h @ w2 (partial j-chunks, atomics) ----------------
__global__ __launch_bounds__(64)
void mlp_dw_kernel(const float* __restrict__ h, const float* __restrict__ w2,
                   float* __restrict__ dW) {
    const int blk = blockIdx.x;
    const int dc = blk % 12;
    const int jc = (blk / 12) & 3;
    const int b  = blk / 48;
    const int l  = threadIdx.x;
    __shared__ float hs[64];
    hs[l] = h[b * HDIM + jc * 64 + l];
    __syncthreads();
    const int d = dc * 64 + l;
    const float* w = w2 + (size_t)(jc * 64) * DDIM + d;
    float acc = 0.f;
    #pragma unroll 8
    for (int j = 0; j < 64; ++j) acc = fmaf(hs[j], w[(size_t)j * DDIM], acc);
    atomicAdd(&dW[b * DDIM + d], acc);
}

// ======================= register-resident FFT machinery =======================

__device__ __forceinline__ void cmulc(float& r, float& i, float br, float bi) {
    float tr = r * br - i * bi;
    float ti = r * bi + i * br;
    r = tr; i = ti;
}

// xor-shuffle across 64 lanes: DPP for 1,2; ds_swizzle for 4,8,16; bpermute for 32
template<int MASK>
__device__ __forceinline__ float xsh(float v, int l) {
    int iv = __float_as_int(v);
    if constexpr (MASK == 1)       iv = __builtin_amdgcn_mov_dpp(iv, 0xB1, 0xF, 0xF, false);
    else if constexpr (MASK == 2)  iv = __builtin_amdgcn_mov_dpp(iv, 0x4E, 0xF, 0xF, false);
    else if constexpr (MASK == 32) iv = __builtin_amdgcn_ds_bpermute((l ^ 32) << 2, iv);
    else                           iv = __builtin_amdgcn_ds_swizzle(iv, (MASK << 10) | 0x1F);
    return __int_as_float(iv);
}

// Select-free DIF butterfly stage over index space `idx` (distance M), with data
// of index i living at lane sigma(i) such that pairing i^M == lane xor MASK.
// Forward (INV=false): natural-in -> bitrev-out. In permuted space (idx=rk,
// MASK=32/M): bitrev-in -> natural-out. lo: a+b; hi: (a-b)*W_{2M}^{idx&(M-1)}.
template<int M, int MASK, bool INV>
__device__ __forceinline__ void stageP(float* zr, float* zi, int l, int idx) {
    constexpr float SG = INV ? 1.f : -1.f;
    float wc = 1.f, ws = 0.f;
    if constexpr (M > 1) {
        float jj = (float)(idx & (M - 1));
        __sincosf(SG * (3.14159265358979323846f / M) * jj, &ws, &wc);
    }
    const bool hi = (idx & M) != 0;
    const float sgn = hi ? -1.f : 1.f;
    const float wc2 = hi ? wc : 1.f;
    const float ws2 = hi ? ws : 0.f;
    #pragma unroll
    for (int j = 0; j < 12; ++j) {
        float pr = xsh<MASK>(zr[j], l), pi = xsh<MASK>(zi[j], l);
        float tr = fmaf(sgn, zr[j], pr);
        float ti = fmaf(sgn, zi[j], pi);
        zr[j] = wc2 * tr - ws2 * ti;
        zi[j] = wc2 * ti + ws2 * tr;
    }
}

// 12-point DFT over registers (input reg n1, output reg k1; INV conjugates)
template<bool INV>
__device__ __forceinline__ void dft12(float* zr, float* zi) {
    constexpr float C1 = 0.8660254037844386f;
    constexpr float SG = INV ? 1.f : -1.f;
    constexpr float E  = INV ? -C1 : C1;
    float sr[3][4], si[3][4];
    #pragma unroll
    for (int b = 0; b < 3; ++b) {
        float x0r = zr[b],     x0i = zi[b];
        float x1r = zr[3 + b], x1i = zi[3 + b];
        float x2r = zr[6 + b], x2i = zi[6 + b];
        float x3r = zr[9 + b], x3i = zi[9 + b];
        float t0r = x0r + x2r, t0i = x0i + x2i;
        float t1r = x0r - x2r, t1i = x0i - x2i;
        float t2r = x1r + x3r, t2i = x1i + x3i;
        float t3r = x1r - x3r, t3i = x1i - x3i;
        sr[b][0] = t0r + t2r; si[b][0] = t0i + t2i;
        sr[b][2] = t0r - t2r; si[b][2] = t0i - t2i;
        if constexpr (!INV) {
            sr[b][1] = t1r + t3i; si[b][1] = t1i - t3r;
            sr[b][3] = t1r - t3i; si[b][3] = t1i + t3r;
        } else {
            sr[b][1] = t1r - t3i; si[b][1] = t1i + t3r;
            sr[b][3] = t1r + t3i; si[b][3] = t1i - t3r;
        }
    }
    cmulc(sr[1][1], si[1][1], C1,  SG * 0.5f);
    cmulc(sr[1][2], si[1][2], 0.5f, SG * C1);
    { float t = sr[1][3]; sr[1][3] = -SG * si[1][3]; si[1][3] = SG * t; }
    cmulc(sr[2][1], si[2][1], 0.5f,  SG * C1);
    cmulc(sr[2][2], si[2][2], -0.5f, SG * C1);
    sr[2][3] = -sr[2][3]; si[2][3] = -si[2][3];
    #pragma unroll
    for (int p = 0; p < 4; ++p) {
        float x0r = sr[0][p], x0i = si[0][p];
        float x1r = sr[1][p], x1i = si[1][p];
        float x2r = sr[2][p], x2i = si[2][p];
        float tr = x1r + x2r, ti = x1i + x2i;
        float ur = x1r - x2r, ui = x1i - x2i;
        float br = x0r - 0.5f * tr, bi = x0i - 0.5f * ti;
        zr[p]     = x0r + tr;        zi[p]     = x0i + ti;
        zr[4 + p] = br + E * ui;     zi[4 + p] = bi - E * ur;
        zr[8 + p] = br - E * ui;     zi[8 + p] = bi + E * ur;
    }
}

// modReLU effective multiplier, algebraic form:
// w*relu(|w|m+b)/(|w|m) = (|w|m+b > 0) ? w + sign(w)*b*inv_m : 0
__device__ __forceinline__ float geff2(float w, float m, float inv_m, float b) {
    float g = fmaf(__builtin_copysignf(1.0f, w), b * inv_m, w);
    return (fmaf(fabsf(w), m, b) > 0.0f) ? g : 0.0f;
}

// filter math for one spectral slot: Zk=(Zkr,Zki), partner Zn=(Znr,Zni), index kx
__device__ __forceinline__ void filt_core(
    float Zkr, float Zki, float Znr, float Zni, int kx,
    const float* __restrict__ wb1, const float* __restrict__ wb2,
    const float* __restrict__ dwb, const float* __restrict__ bias,
    float& outR, float& outI) {
    const int nk = kx ? (DDIM - kx) : 0;
    float F1r = 0.5f * (Zkr + Znr), F1i = 0.5f * (Zki - Zni);
    float F2r = 0.5f * (Zki + Zni), F2i = 0.5f * (Znr - Zkr);
    float s1 = fmaxf(fmaf(F1r, F1r, F1i * F1i), 1e-24f);
    float s2 = fmaxf(fmaf(F2r, F2r, F2i * F2i), 1e-24f);
    float im1 = rsqrtf(s1), im2 = rsqrtf(s2);
    float m1 = s1 * im1,   m2 = s2 * im2;
    float dk = dwb[kx], dn = dwb[nk];
    float bk = bias[kx], bn = bias[nk];
    float w1k = wb1[kx] + dk, w1n = wb1[nk] + dn;
    float w2k = wb2[kx] + dk, w2n = wb2[nk] + dn;
    float g1 = 0.5f * (geff2(w1k, m1, im1, bk) + geff2(w1n, m1, im1, bn));
    float g2 = 0.5f * (geff2(w2k, m2, im2, bk) + geff2(w2n, m2, im2, bn));
    outR = g1 * F1r - g2 * F2i;
    outI = g1 * F1i + g2 * F2r;
}

// one filter PAIR step, members A=J and B=11-J processed together (slot kx = 64*reg + rk).
// Wave partner of reg A is reg B's OLD value at lane src (and vice versa) -> no snapshot.
// rk==0 (<=> l==0): partner of A is old reg (12-J)%12 at lane 0 -> 2-reg rolling save;
// partner of B is old reg J+1 (future pair, still old), except J=5 (reg-6 self-pair).
template<int J>
__device__ __forceinline__ void filt_pair(
    float* zr, float* zi, float& svR, float& svI,
    int l, int rk, int src,
    const float* __restrict__ wb1, const float* __restrict__ wb2,
    const float* __restrict__ dwb, const float* __restrict__ bias) {
    constexpr int A = J, B = 11 - J;
    const float aZr = zr[A], aZi = zi[A];   // old A
    const float bZr = zr[B], bZi = zi[B];   // old B
    float paR = __int_as_float(__builtin_amdgcn_ds_bpermute(src, __float_as_int(bZr)));
    float paI = __int_as_float(__builtin_amdgcn_ds_bpermute(src, __float_as_int(bZi)));
    float pbR = __int_as_float(__builtin_amdgcn_ds_bpermute(src, __float_as_int(aZr)));
    float pbI = __int_as_float(__builtin_amdgcn_ds_bpermute(src, __float_as_int(aZi)));
    float a0r, a0i;
    if constexpr (J == 0) { a0r = aZr; a0i = aZi; }      // k=0 self-pair
    else                  { a0r = svR; a0i = svI; }      // old reg 12-J from prev pair
    float b0r, b0i;
    if constexpr (J == 5) { b0r = bZr; b0i = bZi; }      // k=384 self-pair (reg 6)
    else                  { b0r = zr[J + 1]; b0i = zi[J + 1]; }  // future pair, still old
    paR = (l == 0) ? a0r : paR;  paI = (l == 0) ? a0i : paI;
    pbR = (l == 0) ? b0r : pbR;  pbI = (l == 0) ? b0i : pbI;
    svR = bZr; svI = bZi;
    filt_core(aZr, aZi, paR, paI, 64 * A + rk, wb1, wb2, dwb, bias, zr[A], zi[A]);
    filt_core(bZr, bZi, pbR, pbI, 64 * B + rk, wb1, wb2, dwb, bias, zr[B], zi[B]);
}

// ---------------- kernel 3: register-resident FFT -> filter -> iFFT ----------------
// n = n1 + 12*n2 (reg n1, lane n2). Both lane-FFT directions are select-free DIF.
// __launch_bounds__(256,4): the measured optimum of the allocator's tiered trade
// (budget 256/min: min2->no-spill/21% occ, min4->64reg/40% occ <- best, min5/8 spill).
__global__ __launch_bounds__(256, 4)
void fftmix_kernel(const float* __restrict__ x, const float* __restrict__ Wb,
                   const float* __restrict__ dW, const float* __restrict__ bias,
                   float* __restrict__ out) {
    const int l  = threadIdx.x & 63;
    const int wv = threadIdx.x >> 6;
    const int pair = blockIdx.x * 4 + wv;     // [0, 16384)
    const int r1 = pair * 2;
    const int bb = r1 >> 12;
    const int sq = r1 & (NSEQ - 1);
    const int rk = __brev((unsigned)l) >> 26; // bitrev6(l) = k2 this lane holds post-DIF

    // ---- load z = x[r1] + i*x[r1+1]; lane l owns elements [12*l, 12*l+12) ----
    float zr[12], zi[12];
    {
        const float4* p1 = reinterpret_cast<const float4*>(x + (size_t)r1 * DDIM + 12 * l);
        const float4* p2 = reinterpret_cast<const float4*>(x + (size_t)(r1 + 1) * DDIM + 12 * l);
        float4 a0 = p1[0], a1 = p1[1], a2 = p1[2];
        float4 b0 = p2[0], b1_ = p2[1], b2_ = p2[2];
        zr[0] = a0.x; zr[1] = a0.y; zr[2] = a0.z; zr[3] = a0.w;
        zr[4] = a1.x; zr[5] = a1.y; zr[6] = a1.z; zr[7] = a1.w;
        zr[8] = a2.x; zr[9] = a2.y; zr[10] = a2.z; zr[11] = a2.w;
        zi[0] = b0.x; zi[1] = b0.y; zi[2] = b0.z; zi[3] = b0.w;
        zi[4] = b1_.x; zi[5] = b1_.y; zi[6] = b1_.z; zi[7] = b1_.w;
        zi[8] = b2_.x; zi[9] = b2_.y; zi[10] = b2_.z; zi[11] = b2_.w;
    }

    // ---- forward DIF64 across lanes (natural n2 in -> k2 = rk at lane l) ----
    stageP<32, 32, false>(zr, zi, l, l); stageP<16, 16, false>(zr, zi, l, l);
    stageP<8,  8,  false>(zr, zi, l, l); stageP<4,  4,  false>(zr, zi, l, l);
    stageP<2,  2,  false>(zr, zi, l, l); stageP<1,  1,  false>(zr, zi, l, l);

    // ---- middle twiddle: reg j *= W768^{j * rk} ----
    {
        const float th = -(6.283185307179586f / DDIM) * (float)rk;
        #pragma unroll
        for (int j = 1; j < 12; ++j) {
            float s, c;
            __sincosf(th * (float)j, &s, &c);
            cmulc(zr[j], zi[j], c, s);
        }
    }

    // ---- DFT12 over registers: reg k1 = Z[64*k1 + rk] ----
    dft12<false>(zr, zi);

    // ---- filter + modReLU, Hermitian register-pairs (J, 11-J) together ----
    {
        const int prk = (64 - rk) & 63;                          // partner k2
        const int src = ((__brev((unsigned)prk) >> 26)) << 2;    // its lane * 4
        const float* wb1 = Wb + (size_t)sq * DDIM;
        const float* wb2 = wb1 + DDIM;
        const float* dwb = dW + (size_t)bb * DDIM;   // includes b2
        float svR = 0.f, svI = 0.f;                  // rolling lane-0 save
        filt_pair<0>(zr, zi, svR, svI, l, rk, src, wb1, wb2, dwb, bias);
        filt_pair<1>(zr, zi, svR, svI, l, rk, src, wb1, wb2, dwb, bias);
        filt_pair<2>(zr, zi, svR, svI, l, rk, src, wb1, wb2, dwb, bias);
        filt_pair<3>(zr, zi, svR, svI, l, rk, src, wb1, wb2, dwb, bias);
        filt_pair<4>(zr, zi, svR, svI, l, rk, src, wb1, wb2, dwb, bias);
        filt_pair<5>(zr, zi, svR, svI, l, rk, src, wb1, wb2, dwb, bias);
    }

    // ---- inverse: DFT12 over registers (k1 -> n1) ----
    dft12<true>(zr, zi);

    // ---- inverse twiddle: reg j *= W768^{+j * rk} ----
    {
        const float th = (6.283185307179586f / DDIM) * (float)rk;
        #pragma unroll
        for (int j = 1; j < 12; ++j) {
            float s, c;
            __sincosf(th * (float)j, &s, &c);
            cmulc(zr[j], zi[j], c, s);
        }
    }

    // ---- inverse DIF64 in permuted (rk) space: bitrev in -> NATURAL n2 = l out ----
    stageP<32, 1,  true>(zr, zi, l, rk); stageP<16, 2,  true>(zr, zi, l, rk);
    stageP<8,  4,  true>(zr, zi, l, rk); stageP<4,  8,  true>(zr, zi, l, rk);
    stageP<2,  16, true>(zr, zi, l, rk); stageP<1,  32, true>(zr, zi, l, rk);

    // ---- store: lane l holds y[12*l .. 12*l+12); y1 = Re/768, y2 = Im/768 ----
    {
        constexpr float inv = 1.0f / DDIM;
        float4* o1 = reinterpret_cast<float4*>(out + (size_t)r1 * DDIM + 12 * l);
        float4* o2 = reinterpret_cast<float4*>(out + (size_t)(r1 + 1) * DDIM + 12 * l);
        o1[0] = make_float4(zr[0] * inv, zr[1] * inv, zr[2] * inv, zr[3] * inv);
        o1[1] = make_float4(zr[4] * inv, zr[5] * inv, zr[6] * inv, zr[7] * inv);
        o1[2] = make_float4(zr[8] * inv, zr[9] * inv, zr[10] * inv, zr[11] * inv);
        o2[0] = make_float4(zi[0] * inv, zi[1] * inv, zi[2] * inv, zi[3] * inv);
        o2[1] = make_float4(zi[4] * inv, zi[5] * inv, zi[6] * inv, zi[7] * inv);
        o2[2] = make_float4(zi[8] * inv, zi[9] * inv, zi[10] * inv, zi[11] * inv);
    }
}

extern "C" void kernel_launch(void* const* d_in, const int* in_sizes, int n_in,
                              void* d_out, int out_size, void* d_ws, size_t ws_size,
                              hipStream_t stream) {
    const float* x    = (const float*)d_in[0];
    const float* Wb   = (const float*)d_in[1];
    const float* bias = (const float*)d_in[2];
    const float* w1   = (const float*)d_in[3];
    const float* b1   = (const float*)d_in[4];
    const float* w2   = (const float*)d_in[5];
    const float* b2   = (const float*)d_in[6];
    float* out = (float*)d_out;

    float* csum = (float*)d_ws;                 // B*D floats
    float* dW   = csum + BDIM * DDIM;           // B*D floats = b2 + h@w2
    float* h    = dW + BDIM * DDIM;             // B*H floats

    hipMemsetAsync(csum, 0, BDIM * DDIM * sizeof(float), stream);
    dwinit_kernel<<<(BDIM * DDIM) / 256, 256, 0, stream>>>(b2, dW);
    colsum_kernel<<<BDIM * CH, 192, 0, stream>>>(x, csum);
    mlp_h_kernel<<<BDIM * HDIM, 64, 0, stream>>>(csum, w1, b1, h);
    mlp_dw_kernel<<<BDIM * 4 * 12, 64, 0, stream>>>(h, w2, dW);
    fftmix_kernel<<<(BDIM * NSEQ / 2) / 4, 256, 0, stream>>>(x, Wb, dW, bias, out);
}